// Round 1
// baseline (1372.175 us; speedup 1.0000x reference)
//
#include <hip/hip_runtime.h>
#include <hip/hip_bf16.h>
#include <stdint.h>

typedef __bf16 bf16_t;
typedef bf16_t bf16x8 __attribute__((ext_vector_type(8)));
typedef float  f32x4  __attribute__((ext_vector_type(4)));

#define DEV static __device__ __forceinline__

constexpr int   BATCH  = 2048;
constexpr int   SEQ    = 64;
constexpr int   DIMC   = 512;
constexpr int   HEADS  = 16;
constexpr int   M_ROWS = BATCH * SEQ;                 // 131072
constexpr float W_GAIN = 0.044194173824159216f;       // 1/sqrt(512)
constexpr float QK_SCALE = 0.17677669529663687f;      // 1/sqrt(32)

DEV void async_copy16(const void* gp, void* lp) {
  __builtin_amdgcn_global_load_lds((__attribute__((address_space(1))) void*)(gp),
                                   (__attribute__((address_space(3))) void*)(lp),
                                   16, 0, 0);
}

DEV f32x4 mfma16(bf16x8 a, bf16x8 b, f32x4 c) {
  return __builtin_amdgcn_mfma_f32_16x16x32_bf16(a, b, c, 0, 0, 0);
}

// ---------------- prep: L2 row norm, bf16 cast ----------------
__global__ __launch_bounds__(256) void k_prep(const float* __restrict__ x,
                                              bf16_t* __restrict__ nx,
                                              float* __restrict__ norms) {
  const int wid = threadIdx.x >> 6, lane = threadIdx.x & 63;
  const int row = blockIdx.x * 4 + wid;
  const float4* xr = (const float4*)(x + (size_t)row * DIMC);
  float4 v0 = xr[lane * 2 + 0];
  float4 v1 = xr[lane * 2 + 1];
  float ss = v0.x*v0.x + v0.y*v0.y + v0.z*v0.z + v0.w*v0.w
           + v1.x*v1.x + v1.y*v1.y + v1.z*v1.z + v1.w*v1.w;
#pragma unroll
  for (int o = 1; o < 64; o <<= 1) ss += __shfl_xor(ss, o);
  const float nrm = fmaxf(sqrtf(ss), 1e-12f);
  const float inv = 1.0f / nrm;
  bf16x8 o;
  o[0] = (bf16_t)(v0.x * inv); o[1] = (bf16_t)(v0.y * inv);
  o[2] = (bf16_t)(v0.z * inv); o[3] = (bf16_t)(v0.w * inv);
  o[4] = (bf16_t)(v1.x * inv); o[5] = (bf16_t)(v1.y * inv);
  o[6] = (bf16_t)(v1.z * inv); o[7] = (bf16_t)(v1.w * inv);
  *(bf16x8*)(nx + (size_t)row * DIMC + lane * 8) = o;
  if (lane == 0) norms[row] = nrm;
}

// ---------------- weight conversion (gain folded) ----------------
__global__ __launch_bounds__(256) void k_convw(const float* __restrict__ qw,
                                               const float* __restrict__ kw,
                                               const float* __restrict__ vw,
                                               const float* __restrict__ pw,
                                               bf16_t* __restrict__ wqkv,
                                               bf16_t* __restrict__ pwb) {
  const int i = blockIdx.x * 256 + threadIdx.x;
  constexpr int QKV_ELEMS = 1536 * 512;
  if (i < QKV_ELEMS) {
    const int n = i >> 9;
    float v = (n < 512) ? qw[i] : (n < 1024) ? kw[i - 512 * 512] : vw[i - 1024 * 512];
    wqkv[i] = (bf16_t)(v * W_GAIN);
  } else {
    const int j = i - QKV_ELEMS;
    pwb[j] = (bf16_t)(pw[j] * W_GAIN);
  }
}

// ---------------- 128x128 BK=32 bf16 GEMM (m97 structure) ----------------
// C[m][n] = sum_k A[m][k] * W[n][k]   (A: [M,512] bf16, W: [NCOLS,512] bf16)
// MODE 0: qkv epilogue (bias select, norm-scale for v cols, bf16 out, ld 1536)
// MODE 1: proj epilogue (pb bias, f32 out, ld 512)
template <int MODE>
__global__ __launch_bounds__(256) void k_gemm(const bf16_t* __restrict__ A,
                                              const bf16_t* __restrict__ Bw,
                                              const float* __restrict__ norms,
                                              const float* __restrict__ qb,
                                              const float* __restrict__ kb,
                                              const float* __restrict__ vb,
                                              bf16_t* __restrict__ Cb,
                                              float* __restrict__ Cf,
                                              const float* __restrict__ pb,
                                              int ntiles_n) {
  __shared__ bf16_t As[128 * 32];
  __shared__ bf16_t Bs[128 * 32];
  const int tid  = threadIdx.x;
  const int wid  = tid >> 6, lane = tid & 63;
  const int tn   = blockIdx.x % ntiles_n;
  const int tm   = blockIdx.x / ntiles_n;
  const int m0   = tm * 128, n0 = tn * 128;
  const int c    = lane & 15, g = lane >> 4;
  const int wr   = (wid >> 1) * 64, wc = (wid & 1) * 64;
  const int sr0  = wid * 16 + (lane >> 2);   // staging row within half-tile
  const int kc8  = (lane & 3) * 8;           // staging k chunk

  f32x4 acc[4][4] = {};

  for (int kt = 0; kt < 16; ++kt) {
    const int k0 = kt * 32;
    // stage A(128x32) and B(128x32); LDS dest = wave-uniform base + lane*16
    async_copy16(A  + (size_t)(m0 + sr0)      * 512 + k0 + kc8, &As[(wid    ) * 512]);
    async_copy16(A  + (size_t)(m0 + 64 + sr0) * 512 + k0 + kc8, &As[(4 + wid) * 512]);
    async_copy16(Bw + (size_t)(n0 + sr0)      * 512 + k0 + kc8, &Bs[(wid    ) * 512]);
    async_copy16(Bw + (size_t)(n0 + 64 + sr0) * 512 + k0 + kc8, &Bs[(4 + wid) * 512]);
    __syncthreads();

    bf16x8 af[4], bfr[4];
#pragma unroll
    for (int mi = 0; mi < 4; ++mi)
      af[mi] = *(const bf16x8*)&As[(wr + mi * 16 + c) * 32 + g * 8];
#pragma unroll
    for (int nj = 0; nj < 4; ++nj)
      bfr[nj] = *(const bf16x8*)&Bs[(wc + nj * 16 + c) * 32 + g * 8];
#pragma unroll
    for (int mi = 0; mi < 4; ++mi)
#pragma unroll
      for (int nj = 0; nj < 4; ++nj)
        acc[mi][nj] = mfma16(af[mi], bfr[nj], acc[mi][nj]);
    __syncthreads();
  }

  if (MODE == 0) {
#pragma unroll
    for (int mi = 0; mi < 4; ++mi) {
#pragma unroll
      for (int r = 0; r < 4; ++r) {
        const int gm = m0 + wr + mi * 16 + g * 4 + r;
        const float nrm = norms[gm];
#pragma unroll
        for (int nj = 0; nj < 4; ++nj) {
          const int gn = n0 + wc + nj * 16 + c;
          const float bias = (gn < 512) ? qb[gn] : (gn < 1024) ? kb[gn - 512] : vb[gn - 1024];
          float v = acc[mi][nj][r];
          if (gn >= 1024) v *= nrm;          // v = norm * (nx @ vw_g^T) + vb
          v += bias;
          Cb[(size_t)gm * 1536 + gn] = (bf16_t)v;
        }
      }
    }
  } else {
#pragma unroll
    for (int mi = 0; mi < 4; ++mi)
#pragma unroll
      for (int nj = 0; nj < 4; ++nj) {
        const int gn = n0 + wc + nj * 16 + c;
        const float bias = pb[gn];
#pragma unroll
        for (int r = 0; r < 4; ++r) {
          const int gm = m0 + wr + mi * 16 + g * 4 + r;
          Cf[(size_t)gm * 512 + gn] = acc[mi][nj][r] + bias;
        }
      }
  }
}

// ---------------- attention: one wave per (b,h) ----------------
__global__ __launch_bounds__(256) void k_attn(const bf16_t* __restrict__ qkv,
                                              const float* __restrict__ wmask,
                                              const float* __restrict__ mwin,
                                              bf16_t* __restrict__ aout) {
  __shared__ bf16_t Pl[4][64 * 72];   // padded: 72 elts/row -> conflict-light a-frag reads
  __shared__ bf16_t Vl[4][64 * 34];   // 34 elts = 17 dwords/row -> conflict-free b-frag gather
  const int wid = threadIdx.x >> 6, lane = threadIdx.x & 63;
  const int gw  = blockIdx.x * 4 + wid;
  const int b   = gw >> 4, h = gw & 15;
  const int c   = lane & 15, g = lane >> 4;
  const size_t base = (size_t)b * 64 * 1536;

  // Q (A frag: row=lane%16, k=8*(lane/16)+t) and K (B frag: col=lane%16, same k)
  bf16x8 qa[4], kf[4];
#pragma unroll
  for (int mi = 0; mi < 4; ++mi)
    qa[mi] = *(const bf16x8*)(qkv + base + (size_t)(mi * 16 + c) * 1536 + h * 32 + g * 8);
#pragma unroll
  for (int nj = 0; nj < 4; ++nj)
    kf[nj] = *(const bf16x8*)(qkv + base + (size_t)(nj * 16 + c) * 1536 + 512 + h * 32 + g * 8);

  // stage V[64][32] into LDS (stride 34)
  {
    const int jr = lane >> 2;
    const int c8 = (lane & 3) * 8;
#pragma unroll
    for (int t = 0; t < 4; ++t) {
      const int row = jr + t * 16;
      bf16x8 v = *(const bf16x8*)(qkv + base + (size_t)row * 1536 + 1024 + h * 32 + c8);
      uint32_t* dst = (uint32_t*)&Vl[wid][row * 34 + c8];
      const uint32_t* src = (const uint32_t*)&v;
      dst[0] = src[0]; dst[1] = src[1]; dst[2] = src[2]; dst[3] = src[3];
    }
  }

  // S = Q @ K^T  (C layout: col=lane&15, row=(lane>>4)*4+r)
  f32x4 s[4][4];
  const f32x4 zero = {0.f, 0.f, 0.f, 0.f};
#pragma unroll
  for (int mi = 0; mi < 4; ++mi)
#pragma unroll
    for (int nj = 0; nj < 4; ++nj)
      s[mi][nj] = mfma16(qa[mi], kf[nj], zero);

  // masks
  float kadd[4];
#pragma unroll
  for (int nj = 0; nj < 4; ++nj) {
    const float mv = mwin[b * 64 + nj * 16 + c];
    kadd[nj] = (mv == 0.0f) ? -100.0f : 0.0f;
  }
  const int w = b & 63;
  const float* wm = wmask + (size_t)w * 4096;
#pragma unroll
  for (int mi = 0; mi < 4; ++mi)
#pragma unroll
    for (int nj = 0; nj < 4; ++nj)
#pragma unroll
      for (int r = 0; r < 4; ++r) {
        const int i = mi * 16 + g * 4 + r;
        s[mi][nj][r] = s[mi][nj][r] * QK_SCALE + wm[i * 64 + nj * 16 + c] + kadd[nj];
      }

  // softmax over keys: 4 local cols + butterfly over 16-lane group
#pragma unroll
  for (int mi = 0; mi < 4; ++mi)
#pragma unroll
    for (int r = 0; r < 4; ++r) {
      float mx = fmaxf(fmaxf(s[mi][0][r], s[mi][1][r]), fmaxf(s[mi][2][r], s[mi][3][r]));
#pragma unroll
      for (int o = 1; o < 16; o <<= 1) mx = fmaxf(mx, __shfl_xor(mx, o));
      float sum = 0.f;
#pragma unroll
      for (int nj = 0; nj < 4; ++nj) {
        const float p = __expf(s[mi][nj][r] - mx);
        s[mi][nj][r] = p;
        sum += p;
      }
#pragma unroll
      for (int o = 1; o < 16; o <<= 1) sum += __shfl_xor(sum, o);
      const float inv = 1.0f / sum;
#pragma unroll
      for (int nj = 0; nj < 4; ++nj) s[mi][nj][r] *= inv;
    }

  // P -> LDS (bf16), then PV via MFMA
#pragma unroll
  for (int mi = 0; mi < 4; ++mi)
#pragma unroll
    for (int nj = 0; nj < 4; ++nj)
#pragma unroll
      for (int r = 0; r < 4; ++r) {
        const int i = mi * 16 + g * 4 + r, j = nj * 16 + c;
        Pl[wid][i * 72 + j] = (bf16_t)s[mi][nj][r];
      }
  // same-wave ds_write -> ds_read: compiler inserts lgkmcnt waits; no barrier needed
  f32x4 o[4][2] = {};
#pragma unroll
  for (int ks = 0; ks < 2; ++ks) {
    bf16x8 pa[4];
#pragma unroll
    for (int mi = 0; mi < 4; ++mi)
      pa[mi] = *(const bf16x8*)&Pl[wid][(mi * 16 + c) * 72 + ks * 32 + g * 8];
#pragma unroll
    for (int nd = 0; nd < 2; ++nd) {
      bf16x8 vf;
#pragma unroll
      for (int t = 0; t < 8; ++t)
        vf[t] = Vl[wid][(ks * 32 + g * 8 + t) * 34 + nd * 16 + c];
#pragma unroll
      for (int mi = 0; mi < 4; ++mi)
        o[mi][nd] = mfma16(pa[mi], vf, o[mi][nd]);
    }
  }

  bf16_t* op = aout + (size_t)b * 64 * 512 + h * 32;
#pragma unroll
  for (int mi = 0; mi < 4; ++mi)
#pragma unroll
    for (int nd = 0; nd < 2; ++nd)
#pragma unroll
      for (int r = 0; r < 4; ++r) {
        const int i = mi * 16 + g * 4 + r;
        op[(size_t)i * 512 + nd * 16 + c] = (bf16_t)o[mi][nd][r];
      }
}

// ---------------- mw output ----------------
__global__ __launch_bounds__(256) void k_mw(const float* __restrict__ mwin,
                                            float* __restrict__ outmw) {
  const int wid = threadIdx.x >> 6, lane = threadIdx.x & 63;
  const int b = blockIdx.x * 4 + wid;
  float v = mwin[b * 64 + lane];
#pragma unroll
  for (int o = 1; o < 64; o <<= 1) v += __shfl_xor(v, o);
  outmw[b * 64 + lane] = fminf(fmaxf(v, 0.0f), 1.0f);
}

extern "C" void kernel_launch(void* const* d_in, const int* in_sizes, int n_in,
                              void* d_out, int out_size, void* d_ws, size_t ws_size,
                              hipStream_t stream) {
  const float* x    = (const float*)d_in[0];
  const float* mask = (const float*)d_in[1];
  const float* mwin = (const float*)d_in[2];
  const float* qw   = (const float*)d_in[3];
  const float* qb   = (const float*)d_in[4];
  const float* kw   = (const float*)d_in[5];
  const float* kb   = (const float*)d_in[6];
  const float* vw   = (const float*)d_in[7];
  const float* vb   = (const float*)d_in[8];
  const float* pw   = (const float*)d_in[9];
  const float* pb   = (const float*)d_in[10];

  float* out   = (float*)d_out;
  float* outmw = out + (size_t)M_ROWS * DIMC;

  char* ws = (char*)d_ws;
  float*  norms = (float*) (ws);                       // 131072 * 4        = 0.5 MB
  bf16_t* wqkv  = (bf16_t*)(ws + 524288);              // 1536*512*2        = 1.5 MB
  bf16_t* pwb   = (bf16_t*)(ws + 2097152);             // 512*512*2         = 0.5 MB
  bf16_t* nx    = (bf16_t*)(ws + 2621440);             // 131072*512*2      = 128 MB
  bf16_t* qkv   = (bf16_t*)(ws + 136839168);           // 131072*1536*2     = 384 MB
  bf16_t* aout  = nx;  // alias: nx is dead after the QKV GEMM

  k_convw<<<4096, 256, 0, stream>>>(qw, kw, vw, pw, wqkv, pwb);
  k_prep<<<M_ROWS / 4, 256, 0, stream>>>(x, nx, norms);
  k_gemm<0><<<(M_ROWS / 128) * 12, 256, 0, stream>>>(nx, wqkv, norms, qb, kb, vb,
                                                     qkv, nullptr, nullptr, 12);
  k_attn<<<BATCH * HEADS / 4, 256, 0, stream>>>(qkv, mask, mwin, aout);
  k_gemm<1><<<(M_ROWS / 128) * 4, 256, 0, stream>>>(aout, pwb, nullptr, nullptr, nullptr, nullptr,
                                                    nullptr, out, pb, 4);
  k_mw<<<BATCH / 4, 256, 0, stream>>>(mwin, outmw);
}

// Round 3
// 1137.659 us; speedup vs baseline: 1.2061x; 1.2061x over previous
//
#include <hip/hip_runtime.h>
#include <hip/hip_bf16.h>
#include <stdint.h>

typedef __bf16 bf16_t;
typedef bf16_t bf16x8 __attribute__((ext_vector_type(8)));
typedef bf16_t bf16x4 __attribute__((ext_vector_type(4)));
typedef float  f32x4  __attribute__((ext_vector_type(4)));

#define DEV static __device__ __forceinline__

constexpr int   BATCH  = 2048;
constexpr int   SEQ    = 64;
constexpr int   DIMC   = 512;
constexpr int   HEADS  = 16;
constexpr int   M_ROWS = BATCH * SEQ;                 // 131072
constexpr float W_GAIN = 0.044194173824159216f;       // 1/sqrt(512)
constexpr float QK_SCALE = 0.17677669529663687f;      // 1/sqrt(32)

DEV void async_copy16(const void* gp, void* lp) {
  __builtin_amdgcn_global_load_lds((__attribute__((address_space(1))) void*)(gp),
                                   (__attribute__((address_space(3))) void*)(lp),
                                   16, 0, 0);
}

DEV f32x4 mfma16(bf16x8 a, bf16x8 b, f32x4 c) {
  return __builtin_amdgcn_mfma_f32_16x16x32_bf16(a, b, c, 0, 0, 0);
}

// ---------------- prep: L2 row norm, bf16 cast ----------------
__global__ __launch_bounds__(256) void k_prep(const float* __restrict__ x,
                                              bf16_t* __restrict__ nx,
                                              float* __restrict__ norms) {
  const int wid = threadIdx.x >> 6, lane = threadIdx.x & 63;
  const int row = blockIdx.x * 4 + wid;
  const float4* xr = (const float4*)(x + (size_t)row * DIMC);
  float4 v0 = xr[lane * 2 + 0];
  float4 v1 = xr[lane * 2 + 1];
  float ss = v0.x*v0.x + v0.y*v0.y + v0.z*v0.z + v0.w*v0.w
           + v1.x*v1.x + v1.y*v1.y + v1.z*v1.z + v1.w*v1.w;
#pragma unroll
  for (int o = 1; o < 64; o <<= 1) ss += __shfl_xor(ss, o);
  const float nrm = fmaxf(sqrtf(ss), 1e-12f);
  const float inv = 1.0f / nrm;
  bf16x8 o;
  o[0] = (bf16_t)(v0.x * inv); o[1] = (bf16_t)(v0.y * inv);
  o[2] = (bf16_t)(v0.z * inv); o[3] = (bf16_t)(v0.w * inv);
  o[4] = (bf16_t)(v1.x * inv); o[5] = (bf16_t)(v1.y * inv);
  o[6] = (bf16_t)(v1.z * inv); o[7] = (bf16_t)(v1.w * inv);
  *(bf16x8*)(nx + (size_t)row * DIMC + lane * 8) = o;
  if (lane == 0) norms[row] = nrm;
}

// ---------------- weight conversion (gain folded) ----------------
__global__ __launch_bounds__(256) void k_convw(const float* __restrict__ qw,
                                               const float* __restrict__ kw,
                                               const float* __restrict__ vw,
                                               const float* __restrict__ pw,
                                               bf16_t* __restrict__ wqkv,
                                               bf16_t* __restrict__ pwb) {
  const int i = blockIdx.x * 256 + threadIdx.x;
  constexpr int QKV_ELEMS = 1536 * 512;
  if (i < QKV_ELEMS) {
    const int n = i >> 9;
    float v = (n < 512) ? qw[i] : (n < 1024) ? kw[i - 512 * 512] : vw[i - 1024 * 512];
    wqkv[i] = (bf16_t)(v * W_GAIN);
  } else {
    const int j = i - QKV_ELEMS;
    pwb[j] = (bf16_t)(pw[j] * W_GAIN);
  }
}

// ---------------- 128x128 BK=32 bf16 GEMM, double-buffered 2-phase ----------------
// C[m][n] = sum_k A[m][k] * W[n][k]   (A: [M,512] bf16, W: [NCOLS,512] bf16)
// MODE 0: qkv epilogue -> q/k tiles to qk[M][1024] (bf16, bias), v tiles
//         TRANSPOSED to vT[b][h][d][n] (norm-scale + bias, 8B vector stores)
// MODE 1: proj epilogue (pb bias, f32 out, ld 512)
template <int MODE>
__global__ __launch_bounds__(256) void k_gemm(const bf16_t* __restrict__ A,
                                              const bf16_t* __restrict__ Bw,
                                              const float* __restrict__ norms,
                                              const float* __restrict__ qb,
                                              const float* __restrict__ kb,
                                              const float* __restrict__ vb,
                                              bf16_t* __restrict__ Cb,
                                              bf16_t* __restrict__ vT,
                                              float* __restrict__ Cf,
                                              const float* __restrict__ pb,
                                              int ntiles_n) {
  __shared__ bf16_t As[2][128 * 32];
  __shared__ bf16_t Bs[2][128 * 32];
  const int tid  = threadIdx.x;
  const int wid  = tid >> 6, lane = tid & 63;
  // XCD-aware swizzle: hw-consecutive blocks (round-robin across the 8 XCD L2s)
  // map to a contiguous chunk of logical ids -> blocks sharing an A-panel
  // (same tm, ntiles_n consecutive ids) land on the same XCD. grid % 8 == 0.
  int bid = blockIdx.x;
  bid = (bid & 7) * ((int)gridDim.x >> 3) + (bid >> 3);
  const int tn   = bid % ntiles_n;
  const int tm   = bid / ntiles_n;
  const int m0   = tm * 128, n0 = tn * 128;
  const int c    = lane & 15, g = lane >> 4;
  const int wr   = (wid >> 1) * 64, wc = (wid & 1) * 64;
  const int sr0  = wid * 16 + (lane >> 2);   // staging row within half-tile
  const int kc8  = (lane & 3) * 8;           // staging k chunk

  f32x4 acc[4][4] = {};

  // stage K-step kt into buffer buf (LDS dest = wave-uniform base + lane*16)
  auto stage = [&](int buf, int kt) {
    const int k0 = kt * 32;
    async_copy16(A  + (size_t)(m0 + sr0)      * 512 + k0 + kc8, &As[buf][(wid    ) * 512]);
    async_copy16(A  + (size_t)(m0 + 64 + sr0) * 512 + k0 + kc8, &As[buf][(4 + wid) * 512]);
    async_copy16(Bw + (size_t)(n0 + sr0)      * 512 + k0 + kc8, &Bs[buf][(wid    ) * 512]);
    async_copy16(Bw + (size_t)(n0 + 64 + sr0) * 512 + k0 + kc8, &Bs[buf][(4 + wid) * 512]);
  };

  stage(0, 0);
  __syncthreads();                       // buf0 ready

#pragma unroll 2
  for (int kt = 0; kt < 16; ++kt) {
    const int cur = kt & 1;
    if (kt + 1 < 16) stage(cur ^ 1, kt + 1);   // issue next-tile loads FIRST
    bf16x8 af[4], bfr[4];
#pragma unroll
    for (int mi = 0; mi < 4; ++mi)
      af[mi] = *(const bf16x8*)&As[cur][(wr + mi * 16 + c) * 32 + g * 8];
#pragma unroll
    for (int nj = 0; nj < 4; ++nj)
      bfr[nj] = *(const bf16x8*)&Bs[cur][(wc + nj * 16 + c) * 32 + g * 8];
#pragma unroll
    for (int mi = 0; mi < 4; ++mi)
#pragma unroll
      for (int nj = 0; nj < 4; ++nj)
        acc[mi][nj] = mfma16(af[mi], bfr[nj], acc[mi][nj]);
    __syncthreads();                     // drains vmcnt -> next buf staged
  }

  if (MODE == 0) {
    if (n0 >= 1024) {
      // -------- v tile: write transposed vT[b][h][d][n], 8B vector stores ----
      const int bwin = (m0 + wr) >> 6;       // window index (64-row windows)
#pragma unroll
      for (int nj = 0; nj < 4; ++nj) {
        const int gnv = (n0 - 1024) + wc + nj * 16 + c;   // 0..511
        const int hh = gnv >> 5, dd = gnv & 31;
        const float bias = vb[gnv];
#pragma unroll
        for (int mi = 0; mi < 4; ++mi) {
          bf16x4 pack;
#pragma unroll
          for (int r = 0; r < 4; ++r) {
            const int gm = m0 + wr + mi * 16 + g * 4 + r;
            pack[r] = (bf16_t)(acc[mi][nj][r] * norms[gm] + bias);
          }
          *(bf16x4*)&vT[(((size_t)bwin * 16 + hh) * 32 + dd) * 64 + mi * 16 + g * 4] = pack;
        }
      }
    } else {
      // -------- q/k tile: row-major qk[M][1024] --------
#pragma unroll
      for (int mi = 0; mi < 4; ++mi)
#pragma unroll
        for (int nj = 0; nj < 4; ++nj) {
          const int gn = n0 + wc + nj * 16 + c;
          const float bias = (gn < 512) ? qb[gn] : kb[gn - 512];
#pragma unroll
          for (int r = 0; r < 4; ++r) {
            const int gm = m0 + wr + mi * 16 + g * 4 + r;
            Cb[(size_t)gm * 1024 + gn] = (bf16_t)(acc[mi][nj][r] + bias);
          }
        }
    }
  } else {
#pragma unroll
    for (int mi = 0; mi < 4; ++mi)
#pragma unroll
      for (int nj = 0; nj < 4; ++nj) {
        const int gn = n0 + wc + nj * 16 + c;
        const float bias = pb[gn];
#pragma unroll
        for (int r = 0; r < 4; ++r) {
          const int gm = m0 + wr + mi * 16 + g * 4 + r;
          Cf[(size_t)gm * 512 + gn] = acc[mi][nj][r] + bias;
        }
      }
  }
}

// ---------------- attention: one wave per (b,h) ----------------
// q/k from qk[M][1024]; V fragments loaded DIRECTLY from vT (no LDS staging),
// prefetched before softmax so global latency hides under the VALU work.
__global__ __launch_bounds__(256) void k_attn(const bf16_t* __restrict__ qk,
                                              const bf16_t* __restrict__ vT,
                                              const float* __restrict__ wmask,
                                              const float* __restrict__ mwin,
                                              bf16_t* __restrict__ aout) {
  __shared__ bf16_t Pl[4][64 * 72];   // padded stride 72 -> conflict-light reads
  const int wid = threadIdx.x >> 6, lane = threadIdx.x & 63;
  const int gw  = blockIdx.x * 4 + wid;
  const int b   = gw >> 4, h = gw & 15;
  const int c   = lane & 15, g = lane >> 4;
  const size_t base = (size_t)b * 64 * 1024;

  // Q (A frag: row=lane%16, k=8*(lane/16)+t) and K (B frag: col=lane%16)
  bf16x8 qa[4], kf[4];
#pragma unroll
  for (int mi = 0; mi < 4; ++mi)
    qa[mi] = *(const bf16x8*)(qk + base + (size_t)(mi * 16 + c) * 1024 + h * 32 + g * 8);
#pragma unroll
  for (int nj = 0; nj < 4; ++nj)
    kf[nj] = *(const bf16x8*)(qk + base + (size_t)(nj * 16 + c) * 1024 + 512 + h * 32 + g * 8);

  // S = Q @ K^T  (C layout: col=lane&15, row=(lane>>4)*4+r)
  f32x4 s[4][4];
  const f32x4 zero = {0.f, 0.f, 0.f, 0.f};
#pragma unroll
  for (int mi = 0; mi < 4; ++mi)
#pragma unroll
    for (int nj = 0; nj < 4; ++nj)
      s[mi][nj] = mfma16(qa[mi], kf[nj], zero);

  // prefetch V fragments (B frag: col=c over d, k=g*8+t over n)
  bf16x8 vf[2][2];
#pragma unroll
  for (int ks = 0; ks < 2; ++ks)
#pragma unroll
    for (int nd = 0; nd < 2; ++nd)
      vf[ks][nd] = *(const bf16x8*)&vT[(((size_t)b * 16 + h) * 32 + nd * 16 + c) * 64
                                       + ks * 32 + g * 8];

  // masks
  float kadd[4];
#pragma unroll
  for (int nj = 0; nj < 4; ++nj) {
    const float mv = mwin[b * 64 + nj * 16 + c];
    kadd[nj] = (mv == 0.0f) ? -100.0f : 0.0f;
  }
  const int w = b & 63;
  const float* wm = wmask + (size_t)w * 4096;
#pragma unroll
  for (int mi = 0; mi < 4; ++mi)
#pragma unroll
    for (int nj = 0; nj < 4; ++nj)
#pragma unroll
      for (int r = 0; r < 4; ++r) {
        const int i = mi * 16 + g * 4 + r;
        s[mi][nj][r] = s[mi][nj][r] * QK_SCALE + wm[i * 64 + nj * 16 + c] + kadd[nj];
      }

  // softmax over keys: 4 local cols + butterfly over 16-lane group
#pragma unroll
  for (int mi = 0; mi < 4; ++mi)
#pragma unroll
    for (int r = 0; r < 4; ++r) {
      float mx = fmaxf(fmaxf(s[mi][0][r], s[mi][1][r]), fmaxf(s[mi][2][r], s[mi][3][r]));
#pragma unroll
      for (int o = 1; o < 16; o <<= 1) mx = fmaxf(mx, __shfl_xor(mx, o));
      float sum = 0.f;
#pragma unroll
      for (int nj = 0; nj < 4; ++nj) {
        const float p = __expf(s[mi][nj][r] - mx);
        s[mi][nj][r] = p;
        sum += p;
      }
#pragma unroll
      for (int o = 1; o < 16; o <<= 1) sum += __shfl_xor(sum, o);
      const float inv = 1.0f / sum;
#pragma unroll
      for (int nj = 0; nj < 4; ++nj) s[mi][nj][r] *= inv;
    }

  // P -> LDS (bf16), then PV via MFMA
#pragma unroll
  for (int mi = 0; mi < 4; ++mi)
#pragma unroll
    for (int nj = 0; nj < 4; ++nj)
#pragma unroll
      for (int r = 0; r < 4; ++r) {
        const int i = mi * 16 + g * 4 + r, j = nj * 16 + c;
        Pl[wid][i * 72 + j] = (bf16_t)s[mi][nj][r];
      }
  // same-wave ds_write -> ds_read: compiler inserts lgkmcnt waits; no barrier
  f32x4 o[4][2] = {};
#pragma unroll
  for (int ks = 0; ks < 2; ++ks) {
    bf16x8 pa[4];
#pragma unroll
    for (int mi = 0; mi < 4; ++mi)
      pa[mi] = *(const bf16x8*)&Pl[wid][(mi * 16 + c) * 72 + ks * 32 + g * 8];
#pragma unroll
    for (int nd = 0; nd < 2; ++nd)
#pragma unroll
      for (int mi = 0; mi < 4; ++mi)
        o[mi][nd] = mfma16(pa[mi], vf[ks][nd], o[mi][nd]);
  }

  bf16_t* op = aout + (size_t)b * 64 * 512 + h * 32;
#pragma unroll
  for (int mi = 0; mi < 4; ++mi)
#pragma unroll
    for (int nd = 0; nd < 2; ++nd)
#pragma unroll
      for (int r = 0; r < 4; ++r) {
        const int i = mi * 16 + g * 4 + r;
        op[(size_t)i * 512 + nd * 16 + c] = (bf16_t)o[mi][nd][r];
      }
}

// ---------------- mw output ----------------
__global__ __launch_bounds__(256) void k_mw(const float* __restrict__ mwin,
                                            float* __restrict__ outmw) {
  const int wid = threadIdx.x >> 6, lane = threadIdx.x & 63;
  const int b = blockIdx.x * 4 + wid;
  float v = mwin[b * 64 + lane];
#pragma unroll
  for (int o = 1; o < 64; o <<= 1) v += __shfl_xor(v, o);
  outmw[b * 64 + lane] = fminf(fmaxf(v, 0.0f), 1.0f);
}

extern "C" void kernel_launch(void* const* d_in, const int* in_sizes, int n_in,
                              void* d_out, int out_size, void* d_ws, size_t ws_size,
                              hipStream_t stream) {
  const float* x    = (const float*)d_in[0];
  const float* mask = (const float*)d_in[1];
  const float* mwin = (const float*)d_in[2];
  const float* qw   = (const float*)d_in[3];
  const float* qb   = (const float*)d_in[4];
  const float* kw   = (const float*)d_in[5];
  const float* kb   = (const float*)d_in[6];
  const float* vw   = (const float*)d_in[7];
  const float* vb   = (const float*)d_in[8];
  const float* pw   = (const float*)d_in[9];
  const float* pb   = (const float*)d_in[10];

  float* out   = (float*)d_out;
  float* outmw = out + (size_t)M_ROWS * DIMC;

  char* ws = (char*)d_ws;
  float*  norms = (float*) (ws);                       // 131072*4          = 0.5 MB
  bf16_t* wqkv  = (bf16_t*)(ws + 524288);              // 1536*512*2        = 1.5 MB
  bf16_t* pwb   = (bf16_t*)(ws + 2097152);             // 512*512*2         = 0.5 MB
  bf16_t* nx    = (bf16_t*)(ws + 2621440);             // 131072*512*2      = 128 MB
  bf16_t* qk    = (bf16_t*)(ws + 136839168);           // 131072*1024*2     = 256 MB
  bf16_t* vT    = (bf16_t*)(ws + 405274624);           // 2048*16*32*64*2   = 64 MB
  bf16_t* aout  = nx;  // alias: nx is dead after the QKV GEMM

  k_convw<<<4096, 256, 0, stream>>>(qw, kw, vw, pw, wqkv, pwb);
  k_prep<<<M_ROWS / 4, 256, 0, stream>>>(x, nx, norms);
  k_gemm<0><<<(M_ROWS / 128) * 12, 256, 0, stream>>>(nx, wqkv, norms, qb, kb, vb,
                                                     qk, vT, nullptr, nullptr, 12);
  k_attn<<<BATCH * HEADS / 4, 256, 0, stream>>>(qk, vT, mask, mwin, aout);
  k_gemm<1><<<(M_ROWS / 128) * 4, 256, 0, stream>>>(aout, pwb, nullptr, nullptr, nullptr, nullptr,
                                                    nullptr, nullptr, out, pb, 4);
  k_mw<<<BATCH / 4, 256, 0, stream>>>(mwin, outmw);
}